// Round 12
// baseline (433.748 us; speedup 1.0000x reference)
//
#include <hip/hip_runtime.h>

typedef unsigned int u32;
typedef unsigned short u16;
typedef __attribute__((ext_vector_type(8))) short bf16x8;
typedef __attribute__((ext_vector_type(4))) float f32x4;

// ---------------- problem constants ----------------
#define NB   2048
#define NV   15
#define NT   16
#define NH   64
#define NLH  40
#define EPER 40
#define NN   (NB*NV)       // 30720
#define NE   (NB*EPER)     // 81920

// ---------------- ws layout (float-element offsets unless noted) ----------------
#define F_DATA 0
#define F_EA   983040
#define P_W1   1064960
#define P_B1   1065088
#define P_WG1  1065152
#define P_BG1  1069248
#define P_G1   1069312
#define P_BE1  1069376
#define P_WG2  1069440
#define P_BG2  1073536
#define P_G2   1073600
#define P_BE2  1073664
#define P_WF   1073728
#define P_BF   1135168
#define P_WIHF 1135232
#define P_WHHF 1145472
#define P_BIHF 1151872
#define P_BHHF 1152032
#define P_WIHB 1152192
#define P_WHHB 1162432
#define P_BIHB 1168832
#define P_BHHB 1168992
#define P_WC1  1169152
#define P_BC1  1170432
#define P_WC2  1170448
#define P_BC2  1170464
#define CVT_TOTAL 1170465
#define WFB_OFF   1170496   // u16 frags: WfB[61440] ++ WgB1[4096] ++ WgB2[4096]
#define WIHT_OFF  1205504   // f32 WihT_f[64][160] ++ WihT_b[64][160]
#define STATS_OFF 1231936   // S1a,S2a,S1b,S2b then SC1,SH1,SC2,SH2 (8*1024)
#define XS_OFF    1240128   // M [2048][240] f32 (dead after gcn2); then Xs f32
#define FLAG_OFF  3337280   // int flag (1 = inputs are bf16)
#define BUFX_BYTE 13349376  // bf16 [NN][1024]: y2
#define BUFY_BYTE 76263936  // bf16 [NN][1024]: y1

#define FR_TOTAL (CVT_TOTAL + 90112 + 4096)   // convert + preswz + stats-zero

__device__ const int d_cum[27] = {
  0, 983040, 1064960, 1065088, 1065152, 1069248, 1069312, 1069376,
  1069440, 1073536, 1073600, 1073664, 1073728, 1135168, 1135232, 1145472,
  1151872, 1152032, 1152192, 1162432, 1168832, 1168992, 1169152, 1170432,
  1170448, 1170464, 1170465};

struct Ptrs { const void* p[26]; };

__device__ inline float b2f(u16 u) { return __uint_as_float(((u32)u) << 16); }
__device__ inline u16 f2b(float f) {
  u32 u = __float_as_uint(f);
  u32 r = (u + 0x7FFFu + ((u >> 16) & 1u)) >> 16;
  return (u16)r;
}
__device__ inline float sigf(float x) { return 1.0f / (1.0f + __expf(-x)); }
__device__ inline float cvt(const void* src, int j, int flag) {
  return flag ? b2f(((const u16*)src)[j]) : ((const float*)src)[j];
}

// ---------------- fused frontend: detect + convert + preswz + stats-zero ---
__global__ void k_frontend(Ptrs ptrs, float* __restrict__ W) {
  __shared__ int s_flag;
  if (threadIdx.x == 0) s_flag = 1;
  __syncthreads();
  {
    float f = b2f(((const u16*)ptrs.p[0])[threadIdx.x]);
    if (!(fabsf(f) < 1000.0f)) atomicAnd(&s_flag, 0);
  }
  __syncthreads();
  int flag = s_flag;
  int gid = blockIdx.x * 256 + threadIdx.x;
  if (gid == 0) *(int*)(W + FLAG_OFF) = flag;
  if (gid < CVT_TOTAL) {
    int ti = 0;
    #pragma unroll
    for (int i = 1; i < 26; ++i) ti += (gid >= d_cum[i]);
    W[gid] = cvt(ptrs.p[ti], gid - d_cum[ti], flag);
  } else if (gid < CVT_TOTAL + 61440) {
    int i = gid - CVT_TOTAL;
    int j = i & 7, lane = (i >> 3) & 63, kt = (i >> 9) & 3, ks = i >> 11;
    int kout = kt * 16 + (lane & 15);
    int m = ks * 32 + ((lane >> 4) << 3) + j;
    ((u16*)(W + WFB_OFF))[i] = f2b(cvt(ptrs.p[12], kout * 960 + m, flag));
  } else if (gid < CVT_TOTAL + 69632) {
    int ii = gid - CVT_TOTAL - 61440;
    int L = ii >> 12, r = ii & 4095;
    int j = r & 7, lane = (r >> 3) & 63, nt = (r >> 9) & 3, ks = (r >> 11) & 1;
    int h = ks * 32 + ((lane >> 4) << 3) + j;
    int k = nt * 16 + (lane & 15);
    ((u16*)(W + WFB_OFF))[61440 + ii] = f2b(cvt(ptrs.p[L ? 8 : 4], h * 64 + k, flag));
  } else if (gid < CVT_TOTAL + 90112) {
    int e = gid - CVT_TOTAL - 69632;
    int which = e / 10240, rem = e % 10240;
    int kk = rem / 160, jj = rem % 160;
    W[WIHT_OFF + e] = cvt(ptrs.p[which ? 18 : 14], jj * 64 + kk, flag);
  } else if (gid < FR_TOTAL) {
    W[STATS_OFF + (gid - CVT_TOTAL - 90112)] = 0.f;
  }
}

// ---------------- build normalized-adjacency M for all graphs --------------
__global__ void k_buildM(const float* __restrict__ W, const int* __restrict__ ei,
                         float* __restrict__ Mout) {
  __shared__ float s_m[960];
  __shared__ float s_deg[64];
  int tid = threadIdx.x;
  int gl = tid >> 6, sub = tid & 63;
  int g = blockIdx.x * 4 + gl;
  float* m = s_m + gl * 240;
  float* deg = s_deg + gl * 16;
  float ew = 0.f; int er = 0, ec = 0;
  if (sub < 40) {
    er = ei[g * 40 + sub] - g * 15;
    ec = ei[NE + g * 40 + sub] - g * 15;
    ew = W[F_EA + g * 40 + sub];
  }
  if (sub >= 40 && sub < 56) deg[sub - 40] = 1.0f;
  #pragma unroll
  for (int c = 0; c < 4; ++c) { int i = sub + c * 64; if (i < 240) m[i] = 0.f; }
  __syncthreads();
  if (sub < 40) atomicAdd(&deg[ec], ew);
  __syncthreads();
  if (sub < 15) deg[sub] = rsqrtf(deg[sub]);
  __syncthreads();
  if (sub < 40) atomicAdd(&m[ec * 16 + er], deg[er] * ew * deg[ec]);
  if (sub >= 40 && sub < 55) {
    float dv = deg[sub - 40];
    atomicAdd(&m[(sub - 40) * 17], dv * dv);
  }
  __syncthreads();
  #pragma unroll
  for (int c = 0; c < 4; ++c) { int i = sub + c * 64; if (i < 240) Mout[g * 240 + i] = m[i]; }
}

// ---------------- fused GCN layer (1 block = 1 graph, 4 waves, MFMA) -------
// Linearity exploited: agg(conv1(d)) = conv1'(M@d, rs); for layer 2,
// agg(bn1(y1)+x) = sc*agg(y1) + rs*sh + aggx. Staging L2 = pure copy.
template<int LAYER>
__global__ __launch_bounds__(256, 3)
void k_gcn(const float* __restrict__ W, const float* __restrict__ Mg,
           const u16* __restrict__ bufIn, u16* __restrict__ bufOut,
           const u16* __restrict__ WgB,
           float* __restrict__ S1, float* __restrict__ S2,
           int bgoff, int scoff, int shoff) {
  __shared__ u16 s_x[15360];     // 30720 B, swizzled [v][t][h] bf16 (byte ^= (t&7)<<4)
  __shared__ float s_m[240];
  __shared__ float s_ad[480];    // M @ data  [vc][f][t]
  __shared__ float s_rs[16];     // M row sums
  __shared__ float s_d[480];     // data slice [v][f][t]
  __shared__ float s_w1[192];    // W1 [64][2] ++ b1 [64]
  __shared__ float s_sc[1024], s_sh[1024];   // BN1 fused scale/shift (L2)

  int g = blockIdx.x, tid = threadIdx.x;

  uint4 ld[8];
  if (LAYER == 2) {
    const uint4* py = (const uint4*)(bufIn + g * 15360);
    #pragma unroll
    for (int c = 0; c < 7; ++c) ld[c] = py[tid + c * 256];
    if (tid < 128) ld[7] = py[tid + 1792];
    ((float4*)s_sc)[tid] = ((const float4*)(W + scoff))[tid];
    ((float4*)s_sh)[tid] = ((const float4*)(W + shoff))[tid];
  }
  if (tid < 60) ((float4*)s_m)[tid] = ((const float4*)(Mg + g * 240))[tid];
  if (tid >= 64 && tid < 184) ((float4*)s_d)[tid - 64] = ((const float4*)(W + F_DATA + g * 480))[tid - 64];
  if (tid >= 192 && tid < 240) ((float4*)s_w1)[tid - 192] = ((const float4*)(W + P_W1))[tid - 192];
  __syncthreads();

  // phase A: ad = M @ d (480 elems), rs = M @ 1
  if (tid < 240) {
    #pragma unroll
    for (int e2 = 0; e2 < 2; ++e2) {
      int e = tid * 2 + e2;
      int vc = e >> 5, c = e & 31;
      float a = 0.f;
      #pragma unroll
      for (int vr = 0; vr < 15; ++vr) a = fmaf(s_m[vc * 16 + vr], s_d[vr * 32 + c], a);
      s_ad[e] = a;
    }
  } else if (tid < 255) {
    int vc = tid - 240;
    float a = 0.f;
    #pragma unroll
    for (int vr = 0; vr < 15; ++vr) a += s_m[vc * 16 + vr];
    s_rs[vc] = a;
  }
  __syncthreads();

  // phase B staging into s_x
  if (LAYER == 1) {
    // aggregated x directly: xa = ad0*W1[h,0] + ad1*W1[h,1] + rs*b1[h]
    #pragma unroll
    for (int c = 0; c < 8; ++c) {
      if (c < 7 || tid < 128) {
        int i = tid + c * 256;
        int v = i >> 7, rem = i & 127, t = rem >> 3, q = rem & 7;
        int h0 = q * 8;
        float d0 = s_ad[v * 32 + t], d1 = s_ad[v * 32 + 16 + t];
        float rsv = s_rs[v];
        u32 pk[4];
        #pragma unroll
        for (int jp = 0; jp < 4; ++jp) {
          int h = h0 + jp * 2;
          float xa = fmaf(d0, s_w1[2 * h],     fmaf(d1, s_w1[2 * h + 1], rsv * s_w1[128 + h]));
          float xb = fmaf(d0, s_w1[2 * h + 2], fmaf(d1, s_w1[2 * h + 3], rsv * s_w1[129 + h]));
          pk[jp] = (u32)f2b(xa) | ((u32)f2b(xb) << 16);
        }
        u32 byte = ((u32)(i * 16)) ^ (((u32)(t & 7)) << 4);
        *(uint4*)((char*)s_x + byte) = make_uint4(pk[0], pk[1], pk[2], pk[3]);
      }
    }
  } else {
    // pure swizzled copy of y1
    #pragma unroll
    for (int c = 0; c < 8; ++c) {
      if (c < 7 || tid < 128) {
        int i = tid + c * 256;
        int t = (i >> 3) & 15;
        u32 byte = ((u32)(i * 16)) ^ (((u32)(t & 7)) << 4);
        *(uint4*)((char*)s_x + byte) = ld[c];
      }
    }
  }
  __syncthreads();

  // phase C (L2 only): agg y1 + combine -> x1_agg, in place, 2 passes
  if (LAYER == 2) {
    u32* sx32 = (u32*)s_x;
    #pragma unroll 1
    for (int pp = 0; pp < 2; ++pp) {
      int p = tid + pp * 256;
      int t = p >> 5, h = (2 * p) & 63;
      int th = t * 64 + h;
      u32 ba = ((u32)(t * 128 + h * 2)) ^ (((u32)(t & 7)) << 4);
      float y0[15], y1v[15];
      #pragma unroll
      for (int v = 0; v < 15; ++v) {
        u32 u = sx32[(ba + v * 2048) >> 2];
        y0[v] = b2f((u16)(u & 0xffff)); y1v[v] = b2f((u16)(u >> 16));
      }
      float sc0 = s_sc[th], sc1v = s_sc[th + 1];
      float sh0 = s_sh[th], sh1v = s_sh[th + 1];
      float w10 = s_w1[2 * h], w11 = s_w1[2 * h + 1];
      float w10b = s_w1[2 * h + 2], w11b = s_w1[2 * h + 3];
      float b1a = s_w1[128 + h], b1b = s_w1[129 + h];
      #pragma unroll
      for (int vc = 0; vc < 15; ++vc) {
        float aY0 = 0.f, aY1 = 0.f;
        #pragma unroll
        for (int vr = 0; vr < 15; ++vr) {
          float m = s_m[vc * 16 + vr];
          aY0 = fmaf(m, y0[vr], aY0);
          aY1 = fmaf(m, y1v[vr], aY1);
        }
        float rsv = s_rs[vc];
        float ad0 = s_ad[vc * 32 + t], ad1 = s_ad[vc * 32 + 16 + t];
        float ax0 = fmaf(ad0, w10,  fmaf(ad1, w11,  rsv * b1a));
        float ax1 = fmaf(ad0, w10b, fmaf(ad1, w11b, rsv * b1b));
        float o0 = fmaf(sc0,  aY0, fmaf(rsv, sh0, ax0));
        float o1 = fmaf(sc1v, aY1, fmaf(rsv, sh1v, ax1));
        sx32[(ba + vc * 2048) >> 2] = (u32)f2b(o0) | ((u32)f2b(o1) << 16);
      }
    }
    __syncthreads();
  }

  // MFMA GEMM: y[v,t,k] = relu(agg[v,t,:] . Wg[:,k] + bg[k]); wave = n-tile
  int wid = tid >> 6, lane = tid & 63;
  int tA = lane & 15, kg = lane >> 4;
  const bf16x8* wb = (const bf16x8*)WgB;
  bf16x8 bf0 = wb[(0 * 4 + wid) * 64 + lane];
  bf16x8 bf1 = wb[(1 * 4 + wid) * 64 + lane];
  int kout = wid * 16 + tA;
  float bias = W[bgoff + kout];
  f32x4 acc[15];
  #pragma unroll
  for (int v = 0; v < 15; ++v) acc[v] = (f32x4){0.f, 0.f, 0.f, 0.f};
  u32 sw = ((u32)(tA & 7)) << 4;
  #pragma unroll
  for (int v = 0; v < 15; ++v) {
    u32 bb = (u32)(v * 2048 + tA * 128 + kg * 16);
    bf16x8 a0 = *(const bf16x8*)(s_x + ((bb ^ sw) >> 1));
    bf16x8 a1 = *(const bf16x8*)(s_x + (((bb + 64) ^ sw) >> 1));
    acc[v] = __builtin_amdgcn_mfma_f32_16x16x32_bf16(a0, bf0, acc[v], 0, 0, 0);
    acc[v] = __builtin_amdgcn_mfma_f32_16x16x32_bf16(a1, bf1, acc[v], 0, 0, 0);
  }

  // epilogue: bounce y through LDS (kg-swizzled) then coalesced uint4 stores
  float s1r[4] = {0.f, 0.f, 0.f, 0.f}, s2r[4] = {0.f, 0.f, 0.f, 0.f};
  __syncthreads();
  #pragma unroll
  for (int v = 0; v < 15; ++v) {
    #pragma unroll
    for (int r = 0; r < 4; ++r) {
      float y = fmaxf(acc[v][r] + bias, 0.f);
      int t = kg * 4 + r;
      u32 byte = ((u32)(v * 2048 + t * 128 + kout * 2)) ^ (((u32)kg) << 5);
      *(u16*)((char*)s_x + byte) = f2b(y);
      s1r[r] += y; s2r[r] += y * y;
    }
  }
  __syncthreads();
  uint4* dst = (uint4*)(bufOut + g * 15360);
  const uint4* src = (const uint4*)s_x;
  #pragma unroll
  for (int c = 0; c < 8; ++c) {
    if (c < 7 || tid < 128) {
      int i = tid + c * 256;
      dst[i] = src[i ^ (((i >> 5) & 3) << 1)];   // undo kg-swizzle
    }
  }
  #pragma unroll
  for (int r = 0; r < 4; ++r) {
    int idx = (kg * 4 + r) * 64 + kout;
    atomicAdd(&S1[idx], s1r[r]);
    atomicAdd(&S2[idx], s2r[r]);
  }
}

// ---------------- finalize BN stats -> fused scale/shift ----------------
__global__ void k_finalize(float* __restrict__ W, int layer) {
  int i = blockIdx.x * 256 + threadIdx.x;
  if (i >= 1024) return;
  int base = STATS_OFF + (layer == 1 ? 0 : 2048);
  int scb  = STATS_OFF + (layer == 1 ? 4096 : 6144);
  float m   = W[base + i] * (1.0f / 30720.0f);
  float var = W[base + 1024 + i] * (1.0f / 30720.0f) - m * m;
  float istd = rsqrtf(var + 1e-5f);
  int h = i & 63;
  float gm = W[(layer == 1 ? P_G1 : P_G2) + h];
  float bt = W[(layer == 1 ? P_BE1 : P_BE2) + h];
  float sc = gm * istd;
  W[scb + i] = sc;
  W[scb + 1024 + i] = bt - m * sc;
}

// ---------------- fc1 via MFMA: in = bn2(y2)+bn1(y1)+x(recomputed) ---------
__global__ __launch_bounds__(256, 3)
void k_fc1(const float* __restrict__ W, const u16* __restrict__ bufY2,
           const u16* __restrict__ bufY1, const u16* __restrict__ WfB,
           float* __restrict__ Xs) {
  __shared__ u16 s_x[15360];
  __shared__ float s_d[480];
  __shared__ float s_w1[192];
  __shared__ float s_t[4096];    // sc1,sh1,sc2,sh2
  int g = blockIdx.x, tid = threadIdx.x;
  #pragma unroll
  for (int k = 0; k < 4; ++k)
    ((float4*)s_t)[tid + k * 256] = ((const float4*)(W + STATS_OFF + 4096))[tid + k * 256];
  if (tid < 120) ((float4*)s_d)[tid] = ((const float4*)(W + F_DATA + g * 480))[tid];
  if (tid >= 128 && tid < 176) ((float4*)s_w1)[tid - 128] = ((const float4*)(W + P_W1))[tid - 128];
  __syncthreads();
  const uint4* py2 = (const uint4*)(bufY2 + g * 15360);
  const uint4* py1 = (const uint4*)(bufY1 + g * 15360);
  #pragma unroll
  for (int c = 0; c < 8; ++c) {
    if (c < 7 || tid < 128) {
      int i = tid + c * 256;
      int v = i >> 7, rem = i & 127, t = rem >> 3, q = rem & 7;
      int h0 = q * 8, th0 = t * 64 + h0;
      uint4 u2 = py2[i], u1 = py1[i];
      u32 u2s[4] = {u2.x, u2.y, u2.z, u2.w}, u1s[4] = {u1.x, u1.y, u1.z, u1.w};
      float d0 = s_d[v * 32 + t], d1 = s_d[v * 32 + 16 + t];
      float4 C0 = *(const float4*)(s_t + th0),        C1 = *(const float4*)(s_t + th0 + 4);
      float4 D0 = *(const float4*)(s_t + 1024 + th0), D1 = *(const float4*)(s_t + 1028 + th0);
      float4 A0 = *(const float4*)(s_t + 2048 + th0), A1 = *(const float4*)(s_t + 2052 + th0);
      float4 B0 = *(const float4*)(s_t + 3072 + th0), B1 = *(const float4*)(s_t + 3076 + th0);
      float sc2[8] = {A0.x, A0.y, A0.z, A0.w, A1.x, A1.y, A1.z, A1.w};
      float sh2[8] = {B0.x, B0.y, B0.z, B0.w, B1.x, B1.y, B1.z, B1.w};
      float sc1[8] = {C0.x, C0.y, C0.z, C0.w, C1.x, C1.y, C1.z, C1.w};
      float sh1[8] = {D0.x, D0.y, D0.z, D0.w, D1.x, D1.y, D1.z, D1.w};
      u32 pk[4];
      #pragma unroll
      for (int jp = 0; jp < 4; ++jp) {
        int j0 = jp * 2, h = h0 + j0;
        float xa = fmaf(d0, s_w1[2 * h],     fmaf(d1, s_w1[2 * h + 1], s_w1[128 + h]));
        float xb = fmaf(d0, s_w1[2 * h + 2], fmaf(d1, s_w1[2 * h + 3], s_w1[129 + h]));
        float x1a = fmaf(b2f((u16)(u1s[jp] & 0xffff)), sc1[j0],     sh1[j0])     + xa;
        float x1b = fmaf(b2f((u16)(u1s[jp] >> 16)),    sc1[j0 + 1], sh1[j0 + 1]) + xb;
        float a = fmaf(b2f((u16)(u2s[jp] & 0xffff)), sc2[j0],     sh2[j0])     + x1a;
        float b = fmaf(b2f((u16)(u2s[jp] >> 16)),    sc2[j0 + 1], sh2[j0 + 1]) + x1b;
        pk[jp] = (u32)f2b(a) | ((u32)f2b(b) << 16);
      }
      u32 byte = ((u32)(i * 16)) ^ (((u32)(t & 7)) << 4);
      *(uint4*)((char*)s_x + byte) = make_uint4(pk[0], pk[1], pk[2], pk[3]);
    }
  }
  __syncthreads();

  int wid = tid >> 6, lane = tid & 63;
  int tA = lane & 15, kg = lane >> 4;
  f32x4 acc = {0.f, 0.f, 0.f, 0.f};
  const bf16x8* wf = (const bf16x8*)WfB;
  #pragma unroll 2
  for (int ks = 0; ks < 30; ++ks) {
    int v = ks >> 1, half = ks & 1;
    u32 byte = (u32)(v * 2048 + tA * 128 + (half * 32 + kg * 8) * 2) ^ (((u32)(tA & 7)) << 4);
    bf16x8 afrag = *(const bf16x8*)(s_x + (byte >> 1));
    bf16x8 bfrag = wf[(ks * 4 + wid) * 64 + lane];
    acc = __builtin_amdgcn_mfma_f32_16x16x32_bf16(afrag, bfrag, acc, 0, 0, 0);
  }
  int kout = wid * 16 + (lane & 15);
  float bias = W[P_BF + kout];
  #pragma unroll
  for (int r = 0; r < 4; ++r) {
    int t = (lane >> 4) * 4 + r;
    Xs[t * 131072 + g * 64 + kout] = fmaxf(acc[r] + bias, 0.0f);
  }
}

// ---------------- LSTM: fused gate-GEMM (registers) + recurrence + head ----
__global__ __launch_bounds__(512)
void k_lstm2(const float* __restrict__ W, const float* __restrict__ Xs,
             void* __restrict__ dout, const int* __restrict__ flagp) {
  extern __shared__ float smem[];
  float* s_whh = smem;            // 40*162 = 6480
  float* s_xs  = smem + 6480;     // [t][b][k] 16*8*64 = 8192
  float* s_h   = smem + 14672;    // 320
  float* s_c   = smem + 14992;    // 320
  float* s_hb  = smem + 15312;    // 320
  float* s_g   = smem + 15632;    // 1280
  float* s_cls = smem + 16912;    // 128  (total 17040 f32 = 68160 B)
  int tid = threadIdx.x, r0 = blockIdx.x * 8;

  for (int i = tid; i < 6400; i += 512) {
    int jj = i / 40, kk = i % 40;
    s_whh[kk * 162 + jj] = W[P_WHHF + i];
  }
  #pragma unroll
  for (int c = 0; c < 4; ++c) {
    int i4 = tid + c * 512;
    int i = i4 * 4;
    int t = i >> 9, b = (i >> 6) & 7, k = i & 63;
    ((float4*)s_xs)[i4] = *(const float4*)(Xs + t * 131072 + (r0 + b) * 64 + k);
  }
  if (tid < 320) { s_h[tid] = 0.f; s_c[tid] = 0.f; }
  __syncthreads();

  int r = tid >> 6, l = tid & 63;
  int l2 = (l < 32) ? l + 128 : l;
  float G0[16], G1[16], G2[16];
  {
    float b0 = W[P_BIHF + l]      + W[P_BHHF + l];
    float b1 = W[P_BIHF + l + 64] + W[P_BHHF + l + 64];
    float b2 = W[P_BIHF + l2]     + W[P_BHHF + l2];
    #pragma unroll
    for (int t = 0; t < 16; ++t) { G0[t] = b0; G1[t] = b1; G2[t] = b2; }
    const float* wih = W + WIHT_OFF;
    const float* xr = s_xs + r * 64;
    for (int kk = 0; kk < 64; ++kk) {
      float w0 = wih[kk * 160 + l];
      float w1 = wih[kk * 160 + l + 64];
      float w2 = wih[kk * 160 + l2];
      #pragma unroll
      for (int t = 0; t < 16; ++t) {
        float xv = xr[t * 512 + kk];
        G0[t] = fmaf(xv, w0, G0[t]);
        G1[t] = fmaf(xv, w1, G1[t]);
        G2[t] = fmaf(xv, w2, G2[t]);
      }
    }
  }

  #pragma unroll
  for (int t = 0; t < 16; ++t) {
    float acc0 = G0[t], acc1 = G1[t], acc2 = G2[t];
    const float* hr = s_h + r * 40;
    #pragma unroll 8
    for (int kk = 0; kk < 40; ++kk) {
      float hv = hr[kk];
      acc0 = fmaf(hv, s_whh[kk * 162 + l], acc0);
      acc1 = fmaf(hv, s_whh[kk * 162 + l + 64], acc1);
      acc2 = fmaf(hv, s_whh[kk * 162 + l2], acc2);
    }
    s_g[r * 160 + l] = acc0;
    s_g[r * 160 + l + 64] = acc1;
    if (l < 32) s_g[r * 160 + l2] = acc2;
    __syncthreads();
    if (tid < 320) {
      int row = tid / 40, jj = tid % 40;
      const float* gr = s_g + row * 160;
      float ig = gr[jj], fg = gr[jj + 40], gg = gr[jj + 80], og = gr[jj + 120];
      float c = sigf(fg) * s_c[tid] + sigf(ig) * tanhf(gg);
      s_c[tid] = c;
      s_h[tid] = sigf(og) * tanhf(c);
    }
    __syncthreads();
  }

  if (tid < 320) {
    int row = tid / 40, jj = tid % 40;
    const float* wb = W + WIHT_OFF + 10240;
    float ai = W[P_BIHB + jj]       + W[P_BHHB + jj];
    float ag = W[P_BIHB + jj + 80]  + W[P_BHHB + jj + 80];
    float ao = W[P_BIHB + jj + 120] + W[P_BHHB + jj + 120];
    const float* xr = s_xs + 15 * 512 + row * 64;
    for (int kk = 0; kk < 64; ++kk) {
      float xv = xr[kk];
      ai = fmaf(xv, wb[kk * 160 + jj], ai);
      ag = fmaf(xv, wb[kk * 160 + jj + 80], ag);
      ao = fmaf(xv, wb[kk * 160 + jj + 120], ao);
    }
    float c = sigf(ai) * tanhf(ag);
    s_hb[tid] = sigf(ao) * tanhf(c);
  }
  __syncthreads();

  if (tid < 128) {
    int rr = tid >> 4, jj = tid & 15;
    float a = W[P_BC1 + jj];
    for (int p = 0; p < 40; ++p) a = fmaf(W[P_WC1 + jj * 80 + p],      s_h[rr * 40 + p],  a);
    for (int p = 0; p < 40; ++p) a = fmaf(W[P_WC1 + jj * 80 + 40 + p], s_hb[rr * 40 + p], a);
    s_cls[rr * 16 + jj] = fmaxf(a, 0.0f);
  }
  __syncthreads();
  if (tid < 8) {
    float o = W[P_BC2];
    #pragma unroll
    for (int jj = 0; jj < 16; ++jj) o = fmaf(W[P_WC2 + jj], s_cls[tid * 16 + jj], o);
    if (*flagp) ((u16*)dout)[r0 + tid] = f2b(o);
    else        ((float*)dout)[r0 + tid] = o;
  }
}

// ---------------- launch ----------------
extern "C" void kernel_launch(void* const* d_in, const int* in_sizes, int n_in,
                              void* d_out, int out_size, void* d_ws, size_t ws_size,
                              hipStream_t stream) {
  float* W = (float*)d_ws;
  u16* bufX = (u16*)((char*)d_ws + BUFX_BYTE);   // y2
  u16* bufY = (u16*)((char*)d_ws + BUFY_BYTE);   // y1
  u16* WfB  = (u16*)(W + WFB_OFF);
  float* Mg = W + XS_OFF;                        // M lives where Xs will go later
  const int* ei = (const int*)d_in[26];

  (void)hipFuncSetAttribute(reinterpret_cast<const void*>(&k_lstm2),
                            hipFuncAttributeMaxDynamicSharedMemorySize, 68160);

  Ptrs ptrs;
  for (int i = 0; i < 26; ++i) ptrs.p[i] = d_in[i];
  k_frontend<<<(FR_TOTAL + 255) / 256, 256, 0, stream>>>(ptrs, W);
  k_buildM<<<512, 256, 0, stream>>>(W, ei, Mg);
  k_gcn<1><<<NB, 256, 0, stream>>>(W, Mg, nullptr, bufY, WfB + 61440,
      W + STATS_OFF, W + STATS_OFF + 1024, P_BG1, 0, 0);
  k_finalize<<<4, 256, 0, stream>>>(W, 1);
  k_gcn<2><<<NB, 256, 0, stream>>>(W, Mg, bufY, bufX, WfB + 65536,
      W + STATS_OFF + 2048, W + STATS_OFF + 3072, P_BG2,
      STATS_OFF + 4096, STATS_OFF + 5120);
  k_finalize<<<4, 256, 0, stream>>>(W, 2);
  k_fc1<<<NB, 256, 0, stream>>>(W, bufX, bufY, WfB, W + XS_OFF);
  k_lstm2<<<256, 512, 68160, stream>>>(W, W + XS_OFF, d_out, (const int*)(W + FLAG_OFF));
}

// Round 13
// 326.311 us; speedup vs baseline: 1.3292x; 1.3292x over previous
//
#include <hip/hip_runtime.h>

typedef unsigned int u32;
typedef unsigned short u16;
typedef __attribute__((ext_vector_type(8))) short bf16x8;
typedef __attribute__((ext_vector_type(4))) float f32x4;

// ---------------- problem constants ----------------
#define NB   2048
#define NV   15
#define NT   16
#define NH   64
#define NLH  40
#define EPER 40
#define NN   (NB*NV)       // 30720
#define NE   (NB*EPER)     // 81920

// ---------------- ws layout (float-element offsets unless noted) ----------------
#define F_DATA 0
#define F_EA   983040
#define P_W1   1064960
#define P_B1   1065088
#define P_WG1  1065152
#define P_BG1  1069248
#define P_G1   1069312
#define P_BE1  1069376
#define P_WG2  1069440
#define P_BG2  1073536
#define P_G2   1073600
#define P_BE2  1073664
#define P_WF   1073728
#define P_BF   1135168
#define P_WIHF 1135232
#define P_WHHF 1145472
#define P_BIHF 1151872
#define P_BHHF 1152032
#define P_WIHB 1152192
#define P_WHHB 1162432
#define P_BIHB 1168832
#define P_BHHB 1168992
#define P_WC1  1169152
#define P_BC1  1170432
#define P_WC2  1170448
#define P_BC2  1170464
#define CVT_TOTAL 1170465
#define WFB_OFF   1170496   // u16 frags: WfB[61440] ++ WgB1[4096] ++ WgB2[4096]
#define WIHT_OFF  1205504   // f32 WihT_f[64][160] ++ WihT_b[64][160]
#define STATS_OFF 1231936   // S1a,S2a,S1b,S2b then SC1,SH1,SC2,SH2 (8*1024)
#define XS_OFF    1240128   // M [2048][240] f32 (dead after gcn2); then Xs f32
#define FLAG_OFF  3337280   // int flag (1 = inputs are bf16)
#define BUFX_BYTE 13349376  // bf16 [NN][1024]: y2
#define BUFY_BYTE 76263936  // bf16 [NN][1024]: y1

#define FR_TOTAL (CVT_TOTAL + 90112 + 4096)   // convert + preswz + stats-zero

__device__ const int d_cum[27] = {
  0, 983040, 1064960, 1065088, 1065152, 1069248, 1069312, 1069376,
  1069440, 1073536, 1073600, 1073664, 1073728, 1135168, 1135232, 1145472,
  1151872, 1152032, 1152192, 1162432, 1168832, 1168992, 1169152, 1170432,
  1170448, 1170464, 1170465};

struct Ptrs { const void* p[26]; };

__device__ inline float b2f(u16 u) { return __uint_as_float(((u32)u) << 16); }
__device__ inline u16 f2b(float f) {
  u32 u = __float_as_uint(f);
  u32 r = (u + 0x7FFFu + ((u >> 16) & 1u)) >> 16;
  return (u16)r;
}
__device__ inline float sigf(float x) { return 1.0f / (1.0f + __expf(-x)); }
__device__ inline float cvt(const void* src, int j, int flag) {
  return flag ? b2f(((const u16*)src)[j]) : ((const float*)src)[j];
}

// ---------------- fused frontend: detect + convert + preswz + stats-zero ---
__global__ void k_frontend(Ptrs ptrs, float* __restrict__ W) {
  __shared__ int s_flag;
  if (threadIdx.x == 0) s_flag = 1;
  __syncthreads();
  {
    float f = b2f(((const u16*)ptrs.p[0])[threadIdx.x]);
    if (!(fabsf(f) < 1000.0f)) atomicAnd(&s_flag, 0);
  }
  __syncthreads();
  int flag = s_flag;
  int gid = blockIdx.x * 256 + threadIdx.x;
  if (gid == 0) *(int*)(W + FLAG_OFF) = flag;
  if (gid < CVT_TOTAL) {
    int ti = 0;
    #pragma unroll
    for (int i = 1; i < 26; ++i) ti += (gid >= d_cum[i]);
    W[gid] = cvt(ptrs.p[ti], gid - d_cum[ti], flag);
  } else if (gid < CVT_TOTAL + 61440) {
    int i = gid - CVT_TOTAL;
    int j = i & 7, lane = (i >> 3) & 63, kt = (i >> 9) & 3, ks = i >> 11;
    int kout = kt * 16 + (lane & 15);
    int m = ks * 32 + ((lane >> 4) << 3) + j;
    ((u16*)(W + WFB_OFF))[i] = f2b(cvt(ptrs.p[12], kout * 960 + m, flag));
  } else if (gid < CVT_TOTAL + 69632) {
    int ii = gid - CVT_TOTAL - 61440;
    int L = ii >> 12, r = ii & 4095;
    int j = r & 7, lane = (r >> 3) & 63, nt = (r >> 9) & 3, ks = (r >> 11) & 1;
    int h = ks * 32 + ((lane >> 4) << 3) + j;
    int k = nt * 16 + (lane & 15);
    ((u16*)(W + WFB_OFF))[61440 + ii] = f2b(cvt(ptrs.p[L ? 8 : 4], h * 64 + k, flag));
  } else if (gid < CVT_TOTAL + 90112) {
    int e = gid - CVT_TOTAL - 69632;
    int which = e / 10240, rem = e % 10240;
    int kk = rem / 160, jj = rem % 160;
    W[WIHT_OFF + e] = cvt(ptrs.p[which ? 18 : 14], jj * 64 + kk, flag);
  } else if (gid < FR_TOTAL) {
    W[STATS_OFF + (gid - CVT_TOTAL - 90112)] = 0.f;
  }
}

// ---------------- build normalized-adjacency M for all graphs --------------
__global__ void k_buildM(const float* __restrict__ W, const int* __restrict__ ei,
                         float* __restrict__ Mout) {
  __shared__ float s_m[960];
  __shared__ float s_deg[64];
  int tid = threadIdx.x;
  int gl = tid >> 6, sub = tid & 63;
  int g = blockIdx.x * 4 + gl;
  float* m = s_m + gl * 240;
  float* deg = s_deg + gl * 16;
  float ew = 0.f; int er = 0, ec = 0;
  if (sub < 40) {
    er = ei[g * 40 + sub] - g * 15;
    ec = ei[NE + g * 40 + sub] - g * 15;
    ew = W[F_EA + g * 40 + sub];
  }
  if (sub >= 40 && sub < 56) deg[sub - 40] = 1.0f;
  #pragma unroll
  for (int c = 0; c < 4; ++c) { int i = sub + c * 64; if (i < 240) m[i] = 0.f; }
  __syncthreads();
  if (sub < 40) atomicAdd(&deg[ec], ew);
  __syncthreads();
  if (sub < 15) deg[sub] = rsqrtf(deg[sub]);
  __syncthreads();
  if (sub < 40) atomicAdd(&m[ec * 16 + er], deg[er] * ew * deg[ec]);
  if (sub >= 40 && sub < 55) {
    float dv = deg[sub - 40];
    atomicAdd(&m[(sub - 40) * 17], dv * dv);
  }
  __syncthreads();
  #pragma unroll
  for (int c = 0; c < 4; ++c) { int i = sub + c * 64; if (i < 240) Mout[g * 240 + i] = m[i]; }
}

// ---------------- fused GCN layer (1 block = 1 graph, 4 waves, MFMA) -------
// LAYER 1: linearity — agg(conv1(d)) = conv1'(M@d, M@1); NO agg phase.
// LAYER 2: round-11 proven path (staging bn1(y1)+x, in-place agg, MFMA).
template<int LAYER>
__global__ __launch_bounds__(256, 4)
void k_gcn(const float* __restrict__ W, const float* __restrict__ Mg,
           const u16* __restrict__ bufIn, u16* __restrict__ bufOut,
           const u16* __restrict__ WgB,
           float* __restrict__ S1, float* __restrict__ S2,
           int bgoff, int scoff, int shoff) {
  __shared__ u16 s_x[15360];     // 30720 B, swizzled [v][t][h] bf16 (byte ^= (t&7)<<4)
  __shared__ float s_m[240];
  __shared__ float s_d[480];     // data slice [v][f][t]
  __shared__ float s_w1[192];    // W1 [64][2] ++ b1 [64]
  __shared__ float s_ad[(LAYER == 1) ? 480 : 4];   // M @ data (L1 only)
  __shared__ float s_rs[16];                        // M row sums (L1 only)

  int g = blockIdx.x, tid = threadIdx.x;

  uint4 ld[8];
  if (LAYER == 2) {
    const uint4* py = (const uint4*)(bufIn + g * 15360);
    #pragma unroll
    for (int c = 0; c < 7; ++c) ld[c] = py[tid + c * 256];
    if (tid < 128) ld[7] = py[tid + 1792];
  }

  if (tid < 60) ((float4*)s_m)[tid] = ((const float4*)(Mg + g * 240))[tid];
  if (tid >= 64 && tid < 184) ((float4*)s_d)[tid - 64] = ((const float4*)(W + F_DATA + g * 480))[tid - 64];
  if (tid >= 192 && tid < 240) ((float4*)s_w1)[tid - 192] = ((const float4*)(W + P_W1))[tid - 192];
  __syncthreads();

  if (LAYER == 1) {
    // phase A: ad = M @ d (480 elems), rs = M @ 1
    if (tid < 240) {
      #pragma unroll
      for (int e2 = 0; e2 < 2; ++e2) {
        int e = tid * 2 + e2;
        int vc = e >> 5, c = e & 31;
        float a = 0.f;
        #pragma unroll
        for (int vr = 0; vr < 15; ++vr) a = fmaf(s_m[vc * 16 + vr], s_d[vr * 32 + c], a);
        s_ad[e] = a;
      }
    } else if (tid < 255) {
      int vc = tid - 240;
      float a = 0.f;
      #pragma unroll
      for (int vr = 0; vr < 15; ++vr) a += s_m[vc * 16 + vr];
      s_rs[vc] = a;
    }
    __syncthreads();
  }

  // staging into s_x
  if (LAYER == 1) {
    // aggregated x directly: xa = ad0*W1[h,0] + ad1*W1[h,1] + rs*b1[h]
    #pragma unroll
    for (int c = 0; c < 8; ++c) {
      if (c < 7 || tid < 128) {
        int i = tid + c * 256;
        int v = i >> 7, rem = i & 127, t = rem >> 3, q = rem & 7;
        int h0 = q * 8;
        float d0 = s_ad[v * 32 + t], d1 = s_ad[v * 32 + 16 + t];
        float rsv = s_rs[v];
        u32 pk[4];
        #pragma unroll
        for (int jp = 0; jp < 4; ++jp) {
          int h = h0 + jp * 2;
          float xa = fmaf(d0, s_w1[2 * h],     fmaf(d1, s_w1[2 * h + 1], rsv * s_w1[128 + h]));
          float xb = fmaf(d0, s_w1[2 * h + 2], fmaf(d1, s_w1[2 * h + 3], rsv * s_w1[129 + h]));
          pk[jp] = (u32)f2b(xa) | ((u32)f2b(xb) << 16);
        }
        u32 byte = ((u32)(i * 16)) ^ (((u32)(t & 7)) << 4);
        *(uint4*)((char*)s_x + byte) = make_uint4(pk[0], pk[1], pk[2], pk[3]);
      }
    }
  } else {
    // x1 = bn1(y1) + x (x recomputed from s_d), bf16-swizzled into LDS
    #pragma unroll
    for (int c = 0; c < 8; ++c) {
      if (c < 7 || tid < 128) {
        int i = tid + c * 256;
        int v = i >> 7, rem = i & 127, t = rem >> 3, q = rem & 7;
        int h0 = q * 8;
        float d0 = s_d[v * 32 + t], d1 = s_d[v * 32 + 16 + t];
        u32 uys[4] = {ld[c].x, ld[c].y, ld[c].z, ld[c].w};
        int th0 = t * 64 + h0;
        float4 A0 = *(const float4*)(W + scoff + th0), A1 = *(const float4*)(W + scoff + th0 + 4);
        float4 B0 = *(const float4*)(W + shoff + th0), B1 = *(const float4*)(W + shoff + th0 + 4);
        float scs[8] = {A0.x, A0.y, A0.z, A0.w, A1.x, A1.y, A1.z, A1.w};
        float shs[8] = {B0.x, B0.y, B0.z, B0.w, B1.x, B1.y, B1.z, B1.w};
        u32 pk[4];
        #pragma unroll
        for (int jp = 0; jp < 4; ++jp) {
          int j0 = jp * 2, h = h0 + j0;
          float xa = fmaf(d0, s_w1[2 * h],     fmaf(d1, s_w1[2 * h + 1], s_w1[128 + h]));
          float xb = fmaf(d0, s_w1[2 * h + 2], fmaf(d1, s_w1[2 * h + 3], s_w1[129 + h]));
          float a = fmaf(b2f((u16)(uys[jp] & 0xffff)), scs[j0],     shs[j0])     + xa;
          float b = fmaf(b2f((u16)(uys[jp] >> 16)),    scs[j0 + 1], shs[j0 + 1]) + xb;
          pk[jp] = (u32)f2b(a) | ((u32)f2b(b) << 16);
        }
        u32 byte = ((u32)(i * 16)) ^ (((u32)(t & 7)) << 4);
        *(uint4*)((char*)s_x + byte) = make_uint4(pk[0], pk[1], pk[2], pk[3]);
      }
    }
  }
  __syncthreads();

  // aggregation (LAYER 2 only), in place: each thread owns 4 columns
  if (LAYER == 2) {
    u32* sx32 = (u32*)s_x;
    float x0[15], x1[15], x2[15], x3[15];
    int p0 = tid, p1 = tid + 256;
    int t0 = p0 >> 5, h0 = (2 * p0) & 63;
    int t1 = p1 >> 5, h1 = (2 * p1) & 63;
    u32 ba0 = ((u32)(t0 * 128 + h0 * 2)) ^ (((u32)(t0 & 7)) << 4);
    u32 ba1 = ((u32)(t1 * 128 + h1 * 2)) ^ (((u32)(t1 & 7)) << 4);
    #pragma unroll
    for (int v = 0; v < 15; ++v) {
      u32 ua = sx32[(ba0 + v * 2048) >> 2];
      u32 ub = sx32[(ba1 + v * 2048) >> 2];
      x0[v] = b2f((u16)(ua & 0xffff)); x1[v] = b2f((u16)(ua >> 16));
      x2[v] = b2f((u16)(ub & 0xffff)); x3[v] = b2f((u16)(ub >> 16));
    }
    #pragma unroll
    for (int vc = 0; vc < 15; ++vc) {
      float a0 = 0.f, a1 = 0.f, a2 = 0.f, a3 = 0.f;
      #pragma unroll
      for (int vr = 0; vr < 15; ++vr) {
        float m = s_m[vc * 16 + vr];
        a0 = fmaf(m, x0[vr], a0); a1 = fmaf(m, x1[vr], a1);
        a2 = fmaf(m, x2[vr], a2); a3 = fmaf(m, x3[vr], a3);
      }
      sx32[(ba0 + vc * 2048) >> 2] = (u32)f2b(a0) | ((u32)f2b(a1) << 16);
      sx32[(ba1 + vc * 2048) >> 2] = (u32)f2b(a2) | ((u32)f2b(a3) << 16);
    }
    __syncthreads();
  }

  // MFMA GEMM: y[v,t,k] = relu(agg[v,t,:] . Wg[:,k] + bg[k]); wave = n-tile
  int wid = tid >> 6, lane = tid & 63;
  int tA = lane & 15, kg = lane >> 4;
  const bf16x8* wb = (const bf16x8*)WgB;
  bf16x8 bf0 = wb[(0 * 4 + wid) * 64 + lane];
  bf16x8 bf1 = wb[(1 * 4 + wid) * 64 + lane];
  int kout = wid * 16 + tA;
  float bias = W[bgoff + kout];
  f32x4 acc[15];
  #pragma unroll
  for (int v = 0; v < 15; ++v) acc[v] = (f32x4){0.f, 0.f, 0.f, 0.f};
  u32 sw = ((u32)(tA & 7)) << 4;
  #pragma unroll
  for (int v = 0; v < 15; ++v) {
    u32 bb = (u32)(v * 2048 + tA * 128 + kg * 16);
    bf16x8 a0 = *(const bf16x8*)(s_x + ((bb ^ sw) >> 1));
    bf16x8 a1 = *(const bf16x8*)(s_x + (((bb + 64) ^ sw) >> 1));
    acc[v] = __builtin_amdgcn_mfma_f32_16x16x32_bf16(a0, bf0, acc[v], 0, 0, 0);
    acc[v] = __builtin_amdgcn_mfma_f32_16x16x32_bf16(a1, bf1, acc[v], 0, 0, 0);
  }

  // epilogue: bounce y through LDS (kg-swizzled) then coalesced uint4 stores
  float s1r[4] = {0.f, 0.f, 0.f, 0.f}, s2r[4] = {0.f, 0.f, 0.f, 0.f};
  __syncthreads();
  #pragma unroll
  for (int v = 0; v < 15; ++v) {
    #pragma unroll
    for (int r = 0; r < 4; ++r) {
      float y = fmaxf(acc[v][r] + bias, 0.f);
      int t = kg * 4 + r;
      u32 byte = ((u32)(v * 2048 + t * 128 + kout * 2)) ^ (((u32)kg) << 5);
      *(u16*)((char*)s_x + byte) = f2b(y);
      s1r[r] += y; s2r[r] += y * y;
    }
  }
  __syncthreads();
  uint4* dst = (uint4*)(bufOut + g * 15360);
  const uint4* src = (const uint4*)s_x;
  #pragma unroll
  for (int c = 0; c < 8; ++c) {
    if (c < 7 || tid < 128) {
      int i = tid + c * 256;
      dst[i] = src[i ^ (((i >> 5) & 3) << 1)];   // undo kg-swizzle
    }
  }
  #pragma unroll
  for (int r = 0; r < 4; ++r) {
    int idx = (kg * 4 + r) * 64 + kout;
    atomicAdd(&S1[idx], s1r[r]);
    atomicAdd(&S2[idx], s2r[r]);
  }
}

// ---------------- finalize BN stats -> fused scale/shift ----------------
__global__ void k_finalize(float* __restrict__ W, int layer) {
  int i = blockIdx.x * 256 + threadIdx.x;
  if (i >= 1024) return;
  int base = STATS_OFF + (layer == 1 ? 0 : 2048);
  int scb  = STATS_OFF + (layer == 1 ? 4096 : 6144);
  float m   = W[base + i] * (1.0f / 30720.0f);
  float var = W[base + 1024 + i] * (1.0f / 30720.0f) - m * m;
  float istd = rsqrtf(var + 1e-5f);
  int h = i & 63;
  float gm = W[(layer == 1 ? P_G1 : P_G2) + h];
  float bt = W[(layer == 1 ? P_BE1 : P_BE2) + h];
  float sc = gm * istd;
  W[scb + i] = sc;
  W[scb + 1024 + i] = bt - m * sc;
}

// ---------------- fc1 via MFMA: in = bn2(y2)+bn1(y1)+x(recomputed) ---------
__global__ __launch_bounds__(256, 4)
void k_fc1(const float* __restrict__ W, const u16* __restrict__ bufY2,
           const u16* __restrict__ bufY1, const u16* __restrict__ WfB,
           float* __restrict__ Xs) {
  __shared__ u16 s_x[15360];
  __shared__ float s_d[480];
  __shared__ float s_w1[192];
  int g = blockIdx.x, tid = threadIdx.x;
  if (tid < 120) ((float4*)s_d)[tid] = ((const float4*)(W + F_DATA + g * 480))[tid];
  if (tid >= 128 && tid < 176) ((float4*)s_w1)[tid - 128] = ((const float4*)(W + P_W1))[tid - 128];
  __syncthreads();
  const uint4* py2 = (const uint4*)(bufY2 + g * 15360);
  const uint4* py1 = (const uint4*)(bufY1 + g * 15360);
  #pragma unroll
  for (int c = 0; c < 8; ++c) {
    if (c < 7 || tid < 128) {
      int i = tid + c * 256;
      int v = i >> 7, rem = i & 127, t = rem >> 3, q = rem & 7;
      int h0 = q * 8, th0 = t * 64 + h0;
      uint4 u2 = py2[i], u1 = py1[i];
      u32 u2s[4] = {u2.x, u2.y, u2.z, u2.w}, u1s[4] = {u1.x, u1.y, u1.z, u1.w};
      float d0 = s_d[v * 32 + t], d1 = s_d[v * 32 + 16 + t];
      float4 A0 = *(const float4*)(W + STATS_OFF + 6144 + th0), A1 = *(const float4*)(W + STATS_OFF + 6148 + th0);
      float4 B0 = *(const float4*)(W + STATS_OFF + 7168 + th0), B1 = *(const float4*)(W + STATS_OFF + 7172 + th0);
      float4 C0 = *(const float4*)(W + STATS_OFF + 4096 + th0), C1 = *(const float4*)(W + STATS_OFF + 4100 + th0);
      float4 D0 = *(const float4*)(W + STATS_OFF + 5120 + th0), D1 = *(const float4*)(W + STATS_OFF + 5124 + th0);
      float sc2[8] = {A0.x, A0.y, A0.z, A0.w, A1.x, A1.y, A1.z, A1.w};
      float sh2[8] = {B0.x, B0.y, B0.z, B0.w, B1.x, B1.y, B1.z, B1.w};
      float sc1[8] = {C0.x, C0.y, C0.z, C0.w, C1.x, C1.y, C1.z, C1.w};
      float sh1[8] = {D0.x, D0.y, D0.z, D0.w, D1.x, D1.y, D1.z, D1.w};
      u32 pk[4];
      #pragma unroll
      for (int jp = 0; jp < 4; ++jp) {
        int j0 = jp * 2, h = h0 + j0;
        float xa = fmaf(d0, s_w1[2 * h],     fmaf(d1, s_w1[2 * h + 1], s_w1[128 + h]));
        float xb = fmaf(d0, s_w1[2 * h + 2], fmaf(d1, s_w1[2 * h + 3], s_w1[129 + h]));
        float x1a = fmaf(b2f((u16)(u1s[jp] & 0xffff)), sc1[j0],     sh1[j0])     + xa;
        float x1b = fmaf(b2f((u16)(u1s[jp] >> 16)),    sc1[j0 + 1], sh1[j0 + 1]) + xb;
        float a = fmaf(b2f((u16)(u2s[jp] & 0xffff)), sc2[j0],     sh2[j0])     + x1a;
        float b = fmaf(b2f((u16)(u2s[jp] >> 16)),    sc2[j0 + 1], sh2[j0 + 1]) + x1b;
        pk[jp] = (u32)f2b(a) | ((u32)f2b(b) << 16);
      }
      u32 byte = ((u32)(i * 16)) ^ (((u32)(t & 7)) << 4);
      *(uint4*)((char*)s_x + byte) = make_uint4(pk[0], pk[1], pk[2], pk[3]);
    }
  }
  __syncthreads();

  int wid = tid >> 6, lane = tid & 63;
  int tA = lane & 15, kg = lane >> 4;
  f32x4 acc = {0.f, 0.f, 0.f, 0.f};
  const bf16x8* wf = (const bf16x8*)WfB;
  #pragma unroll 2
  for (int ks = 0; ks < 30; ++ks) {
    int v = ks >> 1, half = ks & 1;
    u32 byte = (u32)(v * 2048 + tA * 128 + (half * 32 + kg * 8) * 2) ^ (((u32)(tA & 7)) << 4);
    bf16x8 afrag = *(const bf16x8*)(s_x + (byte >> 1));
    bf16x8 bfrag = wf[(ks * 4 + wid) * 64 + lane];
    acc = __builtin_amdgcn_mfma_f32_16x16x32_bf16(afrag, bfrag, acc, 0, 0, 0);
  }
  int kout = wid * 16 + (lane & 15);
  float bias = W[P_BF + kout];
  #pragma unroll
  for (int r = 0; r < 4; ++r) {
    int t = (lane >> 4) * 4 + r;
    Xs[t * 131072 + g * 64 + kout] = fmaxf(acc[r] + bias, 0.0f);
  }
}

// ---------------- LSTM: fused gate-GEMM (registers) + recurrence + head ----
__global__ __launch_bounds__(512)
void k_lstm2(const float* __restrict__ W, const float* __restrict__ Xs,
             void* __restrict__ dout, const int* __restrict__ flagp) {
  extern __shared__ float smem[];
  float* s_whh = smem;            // 40*162 = 6480
  float* s_xs  = smem + 6480;     // [t][b][k] 16*8*64 = 8192
  float* s_h   = smem + 14672;    // 320
  float* s_c   = smem + 14992;    // 320
  float* s_hb  = smem + 15312;    // 320
  float* s_g   = smem + 15632;    // 1280
  float* s_cls = smem + 16912;    // 128  (total 17040 f32 = 68160 B)
  int tid = threadIdx.x, r0 = blockIdx.x * 8;

  for (int i = tid; i < 6400; i += 512) {
    int jj = i / 40, kk = i % 40;
    s_whh[kk * 162 + jj] = W[P_WHHF + i];
  }
  #pragma unroll
  for (int c = 0; c < 4; ++c) {
    int i4 = tid + c * 512;
    int i = i4 * 4;
    int t = i >> 9, b = (i >> 6) & 7, k = i & 63;
    ((float4*)s_xs)[i4] = *(const float4*)(Xs + t * 131072 + (r0 + b) * 64 + k);
  }
  if (tid < 320) { s_h[tid] = 0.f; s_c[tid] = 0.f; }
  __syncthreads();

  int r = tid >> 6, l = tid & 63;
  int l2 = (l < 32) ? l + 128 : l;
  float G0[16], G1[16], G2[16];
  {
    float b0 = W[P_BIHF + l]      + W[P_BHHF + l];
    float b1 = W[P_BIHF + l + 64] + W[P_BHHF + l + 64];
    float b2 = W[P_BIHF + l2]     + W[P_BHHF + l2];
    #pragma unroll
    for (int t = 0; t < 16; ++t) { G0[t] = b0; G1[t] = b1; G2[t] = b2; }
    const float* wih = W + WIHT_OFF;
    const float* xr = s_xs + r * 64;
    for (int kk = 0; kk < 64; ++kk) {
      float w0 = wih[kk * 160 + l];
      float w1 = wih[kk * 160 + l + 64];
      float w2 = wih[kk * 160 + l2];
      #pragma unroll
      for (int t = 0; t < 16; ++t) {
        float xv = xr[t * 512 + kk];
        G0[t] = fmaf(xv, w0, G0[t]);
        G1[t] = fmaf(xv, w1, G1[t]);
        G2[t] = fmaf(xv, w2, G2[t]);
      }
    }
  }

  #pragma unroll
  for (int t = 0; t < 16; ++t) {
    float acc0 = G0[t], acc1 = G1[t], acc2 = G2[t];
    const float* hr = s_h + r * 40;
    #pragma unroll 8
    for (int kk = 0; kk < 40; ++kk) {
      float hv = hr[kk];
      acc0 = fmaf(hv, s_whh[kk * 162 + l], acc0);
      acc1 = fmaf(hv, s_whh[kk * 162 + l + 64], acc1);
      acc2 = fmaf(hv, s_whh[kk * 162 + l2], acc2);
    }
    s_g[r * 160 + l] = acc0;
    s_g[r * 160 + l + 64] = acc1;
    if (l < 32) s_g[r * 160 + l2] = acc2;
    __syncthreads();
    if (tid < 320) {
      int row = tid / 40, jj = tid % 40;
      const float* gr = s_g + row * 160;
      float ig = gr[jj], fg = gr[jj + 40], gg = gr[jj + 80], og = gr[jj + 120];
      float c = sigf(fg) * s_c[tid] + sigf(ig) * tanhf(gg);
      s_c[tid] = c;
      s_h[tid] = sigf(og) * tanhf(c);
    }
    __syncthreads();
  }

  if (tid < 320) {
    int row = tid / 40, jj = tid % 40;
    const float* wb = W + WIHT_OFF + 10240;
    float ai = W[P_BIHB + jj]       + W[P_BHHB + jj];
    float ag = W[P_BIHB + jj + 80]  + W[P_BHHB + jj + 80];
    float ao = W[P_BIHB + jj + 120] + W[P_BHHB + jj + 120];
    const float* xr = s_xs + 15 * 512 + row * 64;
    for (int kk = 0; kk < 64; ++kk) {
      float xv = xr[kk];
      ai = fmaf(xv, wb[kk * 160 + jj], ai);
      ag = fmaf(xv, wb[kk * 160 + jj + 80], ag);
      ao = fmaf(xv, wb[kk * 160 + jj + 120], ao);
    }
    float c = sigf(ai) * tanhf(ag);
    s_hb[tid] = sigf(ao) * tanhf(c);
  }
  __syncthreads();

  if (tid < 128) {
    int rr = tid >> 4, jj = tid & 15;
    float a = W[P_BC1 + jj];
    for (int p = 0; p < 40; ++p) a = fmaf(W[P_WC1 + jj * 80 + p],      s_h[rr * 40 + p],  a);
    for (int p = 0; p < 40; ++p) a = fmaf(W[P_WC1 + jj * 80 + 40 + p], s_hb[rr * 40 + p], a);
    s_cls[rr * 16 + jj] = fmaxf(a, 0.0f);
  }
  __syncthreads();
  if (tid < 8) {
    float o = W[P_BC2];
    #pragma unroll
    for (int jj = 0; jj < 16; ++jj) o = fmaf(W[P_WC2 + jj], s_cls[tid * 16 + jj], o);
    if (*flagp) ((u16*)dout)[r0 + tid] = f2b(o);
    else        ((float*)dout)[r0 + tid] = o;
  }
}

// ---------------- launch ----------------
extern "C" void kernel_launch(void* const* d_in, const int* in_sizes, int n_in,
                              void* d_out, int out_size, void* d_ws, size_t ws_size,
                              hipStream_t stream) {
  float* W = (float*)d_ws;
  u16* bufX = (u16*)((char*)d_ws + BUFX_BYTE);   // y2
  u16* bufY = (u16*)((char*)d_ws + BUFY_BYTE);   // y1
  u16* WfB  = (u16*)(W + WFB_OFF);
  float* Mg = W + XS_OFF;                        // M lives where Xs will go later
  const int* ei = (const int*)d_in[26];

  (void)hipFuncSetAttribute(reinterpret_cast<const void*>(&k_lstm2),
                            hipFuncAttributeMaxDynamicSharedMemorySize, 68160);

  Ptrs ptrs;
  for (int i = 0; i < 26; ++i) ptrs.p[i] = d_in[i];
  k_frontend<<<(FR_TOTAL + 255) / 256, 256, 0, stream>>>(ptrs, W);
  k_buildM<<<512, 256, 0, stream>>>(W, ei, Mg);
  k_gcn<1><<<NB, 256, 0, stream>>>(W, Mg, nullptr, bufY, WfB + 61440,
      W + STATS_OFF, W + STATS_OFF + 1024, P_BG1, 0, 0);
  k_finalize<<<4, 256, 0, stream>>>(W, 1);
  k_gcn<2><<<NB, 256, 0, stream>>>(W, Mg, bufY, bufX, WfB + 65536,
      W + STATS_OFF + 2048, W + STATS_OFF + 3072, P_BG2,
      STATS_OFF + 4096, STATS_OFF + 5120);
  k_finalize<<<4, 256, 0, stream>>>(W, 2);
  k_fc1<<<NB, 256, 0, stream>>>(W, bufX, bufY, WfB, W + XS_OFF);
  k_lstm2<<<256, 512, 68160, stream>>>(W, W + XS_OFF, d_out, (const int*)(W + FLAG_OFF));
}